// Round 4
// baseline (810.120 us; speedup 1.0000x reference)
//
#include <hip/hip_runtime.h>

// ---------------------------------------------------------------------------
// HopfieldPooling on MI355X (gfx950)
//   k = x@Wk^T  (split-bf16 MFMA, 3-term; round-1 verified structure:
//       single-buffer LDS A-tile w/ on-stage convert + register prefetch,
//       conflict-free chunk-swizzled layout, B register-direct, XCD swizzle)
//       -> packed (hi|lo<<16) HEAD-MAJOR khead[b][h][n][64]
//   q0 = query@Wq^T (fp32)
//   attn: 3 Hopfield iterations as 3 launches. Each launch: 768 blocks =
//       192 (b,h) x 4 key-chunks of 1024 keys; per-block wave-local rounds
//       (verified layout); partial (sum exp*v, sum exp) atomicAdd'd into
//       global accumulators; reduce kernel normalizes (softmax_1: 1+sum),
//       re-zeroes accumulators, writes q (final iter -> proj layout).
//       4x more blocks than before: all 256 CUs, 2 blocks/CU co-resident.
//   out = (q@Wv^T)@Wproj^T + b  (fp32 vector)
// ---------------------------------------------------------------------------

typedef float  float4v  __attribute__((ext_vector_type(4)));
typedef short  short4v  __attribute__((ext_vector_type(4)));
typedef short  short8v  __attribute__((ext_vector_type(8)));
typedef unsigned int uint4v __attribute__((ext_vector_type(4)));
typedef short8v bf16x8;   // 8 bf16 = 4 VGPRs, MFMA A/B frag

// cheap split: hi = truncated bf16, lo = half-up-rounded bf16 of residual
__device__ __forceinline__ void splitbf(float v, unsigned int& hi, unsigned int& lo){
  unsigned int u = __float_as_uint(v);
  hi = u >> 16;
  float r = v - __uint_as_float(u & 0xffff0000u);
  lo = (__float_as_uint(r) + 0x8000u) >> 16;
}
// packed (hi | lo<<16)
__device__ __forceinline__ unsigned int packbf(float v){
  unsigned int u = __float_as_uint(v);
  float r = v - __uint_as_float(u & 0xffff0000u);
  return (u >> 16) | ((__float_as_uint(r) + 0x8000u) & 0xffff0000u);
}

// ---------------------------------------------------------------------------
// fp32 -> planar hi/lo bf16 (Wk 768x768)
// ---------------------------------------------------------------------------
__global__ __launch_bounds__(256)
void cvt_planar_kernel(const float* __restrict__ src, unsigned short* __restrict__ dh,
                       unsigned short* __restrict__ dl){
  size_t idx = (size_t)blockIdx.x*256 + threadIdx.x;
  float4v v = ((const float4v*)src)[idx];
  short4v h4, l4;
  #pragma unroll
  for(int e=0;e<4;e++){
    unsigned int hh, ll;
    splitbf(v[e], hh, ll);
    h4[e] = (short)hh;
    l4[e] = (short)ll;
  }
  ((short4v*)dh)[idx] = h4;
  ((short4v*)dl)[idx] = l4;
}

// ---------------------------------------------------------------------------
// q0[l][c] = sum_j query[l][j]*Wq[c][j]   (16x768, fp32)
// ---------------------------------------------------------------------------
__global__ __launch_bounds__(256)
void q0_kernel(const float* __restrict__ query, const float* __restrict__ wq,
               float* __restrict__ q0){
  int idx = blockIdx.x*256 + threadIdx.x;     // 12288
  int l = idx / 768, c = idx - l*768;
  const float* qr = query + l*768;
  const float* wr = wq + (size_t)c*768;
  float s = 0.f;
  for(int j=0;j<768;j+=4){
    float4v a  = *(const float4v*)(qr+j);
    float4v w4 = *(const float4v*)(wr+j);
    s += a[0]*w4[0]+a[1]*w4[1]+a[2]*w4[2]+a[3]*w4[3];
  }
  q0[idx] = s;
}

// ---------------------------------------------------------------------------
// zero accumulators (gacc 786432 B + glsum 12288 B contiguous = 199680 f)
// ---------------------------------------------------------------------------
__global__ __launch_bounds__(512)
void zero_kernel(float* __restrict__ p){
  p[(size_t)blockIdx.x*512 + threadIdx.x] = 0.f;
}

// ---------------------------------------------------------------------------
// k = x @ Wk^T.  (round-1 verified version, 276 us, VGPR 64)
//  - A tile in LDS as 16B chunks: chunk(row,c8) = row*4 + (c8 ^ ((row>>2)&3)).
//    Staging writes are stride-1 per quarter-wave (conflict-free); fragment
//    reads spread start-banks 2-way (free).
//  - Next K-step's x loaded into registers right after the 2nd barrier, so
//    HBM/L3 latency hides under the MFMA phase instead of the convert phase.
// ---------------------------------------------------------------------------
__global__ __launch_bounds__(256, 3)
void gemm_k_kernel(const float* __restrict__ x, const unsigned short* __restrict__ wh,
                   const unsigned short* __restrict__ wl, unsigned int* __restrict__ khead){
  __shared__ unsigned short Ah[512*8], Al[512*8];     // 8 KB each, chunk layout
  const int tid  = threadIdx.x;
  const int id   = blockIdx.x;          // 0..3071
  const int xcd  = id & 7, slot = id >> 3;
  const int bml  = slot / 6;            // 0..63
  const int bn   = slot - bml*6;        // 0..5
  const int bm   = xcd*64 + bml;        // 0..511
  const int wave = tid >> 6, lane = tid & 63, quad = lane >> 4, l16 = lane & 15;

  float4v acc[8][2];
  #pragma unroll
  for(int i=0;i<8;i++)
    #pragma unroll
    for(int j=0;j<2;j++) acc[i][j] = (float4v){0.f,0.f,0.f,0.f};

  const float* xA = x + (size_t)bm*128*768;
  const unsigned short* wbh = wh + (size_t)(bn*128 + wave*32 + l16)*768 + quad*8;
  const unsigned short* wbl = wl + (size_t)(bn*128 + wave*32 + l16)*768 + quad*8;

  // staging addressing: thread owns (row0,c8) and (row0+64,c8)
  const int row0 = tid >> 2, c8 = tid & 3;
  const int C0 = row0*4 + (c8 ^ ((row0 >> 2) & 3));   // == wave*64 + lane (stride-1)
  const int C1 = C0 + 256;                            // row0+64: >>2 adds 16 (mod4 = 0)
  const float* g0 = xA + (size_t)row0*768 + c8*8;
  const float* g1 = g0 + (size_t)64*768;
  // fragment-read chunk offset (+ i*64)
  const int crd = l16*4 + (quad ^ ((l16 >> 2) & 3));

  // prologue prefetch (k0 = 0)
  float4v p00 = *(const float4v*)(g0);
  float4v p01 = *(const float4v*)(g0 + 4);
  float4v p10 = *(const float4v*)(g1);
  float4v p11 = *(const float4v*)(g1 + 4);

  for(int k0=0;k0<768;k0+=32){
    bf16x8 b_h[2], b_l[2];
    #pragma unroll
    for(int j=0;j<2;j++){
      b_h[j] = *(const bf16x8*)(wbh + (size_t)j*16*768 + k0);
      b_l[j] = *(const bf16x8*)(wbl + (size_t)j*16*768 + k0);
    }
    __syncthreads();                      // LDS free (prev MFMA done)

    // convert prefetched regs -> LDS (pure VALU + 4 ds_writes)
    {
      short8v hv, lv;
      #pragma unroll
      for(int e=0;e<4;e++){
        unsigned int hh, ll;
        splitbf(p00[e], hh, ll); hv[e]   = (short)hh; lv[e]   = (short)ll;
        splitbf(p01[e], hh, ll); hv[e+4] = (short)hh; lv[e+4] = (short)ll;
      }
      *(short8v*)(Ah + C0*8) = hv;
      *(short8v*)(Al + C0*8) = lv;
      #pragma unroll
      for(int e=0;e<4;e++){
        unsigned int hh, ll;
        splitbf(p10[e], hh, ll); hv[e]   = (short)hh; lv[e]   = (short)ll;
        splitbf(p11[e], hh, ll); hv[e+4] = (short)hh; lv[e+4] = (short)ll;
      }
      *(short8v*)(Ah + C1*8) = hv;
      *(short8v*)(Al + C1*8) = lv;
    }
    __syncthreads();

    // issue next K-step's x loads NOW: in flight across the MFMA phase,
    // drained by the compiler's vmcnt(0) at the next barrier.
    if(k0 + 32 < 768){
      p00 = *(const float4v*)(g0 + k0 + 32);
      p01 = *(const float4v*)(g0 + k0 + 36);
      p10 = *(const float4v*)(g1 + k0 + 32);
      p11 = *(const float4v*)(g1 + k0 + 36);
    }

    #pragma unroll
    for(int i=0;i<8;i++){
      const unsigned short* ap = Ah + (size_t)(i*64 + crd)*8;
      const unsigned short* lp = Al + (size_t)(i*64 + crd)*8;
      bf16x8 a_h = *(const bf16x8*)ap;
      bf16x8 a_l = *(const bf16x8*)lp;
      #pragma unroll
      for(int j=0;j<2;j++){
        acc[i][j] = __builtin_amdgcn_mfma_f32_16x16x32_bf16(a_h, b_h[j], acc[i][j],0,0,0);
        acc[i][j] = __builtin_amdgcn_mfma_f32_16x16x32_bf16(a_l, b_h[j], acc[i][j],0,0,0);
        acc[i][j] = __builtin_amdgcn_mfma_f32_16x16x32_bf16(a_h, b_l[j], acc[i][j],0,0,0);
      }
    }
  }
  // epilogue: head-major packed store. Wave covers 32 cols within one head.
  const int b     = bm >> 5;
  const int Cbase = bn*128 + wave*32;
  const int h     = Cbase >> 6;
  const int dbase = Cbase & 63;        // 0 or 32
  const int nn0   = (bm & 31)*128;
  unsigned int* kout = khead + ((size_t)(b*12 + h)*4096 + nn0)*64 + dbase;
  #pragma unroll
  for(int i=0;i<8;i++)
    #pragma unroll
    for(int j=0;j<2;j++)
      #pragma unroll
      for(int r=0;r<4;r++)
        kout[(size_t)(i*16 + quad*4 + r)*64 + j*16 + l16] = packbf(acc[i][j][r]);
}

// ---------------------------------------------------------------------------
// attn_part: ONE Hopfield iteration over ONE key-chunk of 1024 keys.
// Grid: 768 blocks = (bh 0..191) x (chunk 0..3), 512 threads = 8 waves.
// Per round (4 rounds/block): wave stages ITS OWN 32 rows (global coalesced,
// swizzled LDS), QK (sigma-permuted A rows -> P lands in PV A-layout), exp,
// PV — all wave-local, NO barriers in the round loop (verified layout).
// End: block LDS reduction of acc/lsum, then atomicAdd partials to global.
// softmax_1 fixed shift 0 => chunk partials combine exactly.
// LDS swizzle: phi(r) = ((r&7)<<2) ^ ((r&8)<<1), stride 64 u32.
// ---------------------------------------------------------------------------
__global__ __launch_bounds__(512, 4)
void attn_part_kernel(const unsigned int* __restrict__ khead,
                      const float* __restrict__ q0g,
                      const float* __restrict__ qred,
                      int first,
                      float* __restrict__ gacc, float* __restrict__ glsum){
  __shared__ unsigned int knd[256*64];            // 64 KB exactly
  float* accf  = (float*)knd;                     // [8][1024] at end
  float* lredf = (float*)knd + 8192;              // [8][16]

  const int tid   = threadIdx.x;
  const int bh    = blockIdx.x >> 2;              // 0..191
  const int chunk = blockIdx.x & 3;               // 0..3
  const int h     = bh - (bh/12)*12;
  const int wave  = tid >> 6, lane = tid & 63, quad = lane >> 4, l16 = lane & 15;

  // chunk base: 4 tiles of 256 rows each (tile = 16384 u32)
  const unsigned int* kb = khead + (size_t)bh*4096*64 + (size_t)chunk*4*16384;
  // staging: thread owns tile row tid>>1, u32 half (tid&1)*32
  const int srow = tid >> 1, scol = (tid & 1)*32;
  const int sphi = ((srow & 7) << 2) ^ ((srow & 8) << 1);
  const unsigned int* kbt = kb + (size_t)srow*64 + scol;

  // QK addressing (sigma-permuted rows, wave-local)
  const int rowA = wave*32 + ((l16 >> 2) << 3) + (l16 & 3);
  const int rowB = rowA + 4;
  const int phiA = ((l16 & 3) << 2) ^ (((l16 >> 2) & 1) << 4);
  const int phiB = phiA ^ 16;
  const int q1   = quad & 1;

  // ---- q fragments (scale 1/8 folded), split hi/lo; lane l16 = l ----
  const float* qrow = first ? (q0g + (size_t)l16*768 + h*64)
                            : (qred + (size_t)bh*1024 + l16*64);
  bf16x8 qh[2], ql[2];
  #pragma unroll
  for(int s = 0; s < 2; ++s){
    float4v v0 = *(const float4v*)(qrow + s*32 + quad*8);
    float4v v1 = *(const float4v*)(qrow + s*32 + quad*8 + 4);
    #pragma unroll
    for(int e = 0; e < 8; ++e){
      float v = (e < 4 ? v0[e] : v1[e-4]) * 0.125f;
      unsigned int hh, ll;
      splitbf(v, hh, ll);
      qh[s][e] = (short)hh;
      ql[s][e] = (short)ll;
    }
  }

  // first prefetch (t=0 of this chunk)
  uint4v pf[8];
  #pragma unroll
  for(int g=0; g<8; ++g) pf[g] = *(const uint4v*)(kbt + g*4);

  float4v acc[4];
  #pragma unroll
  for(int j=0;j<4;j++) acc[j] = (float4v){0.f,0.f,0.f,0.f};
  float lsum = 0.f;

  for(int t = 0; t < 4; ++t){
    // ---- stage own 32 rows (swizzled) ----
    #pragma unroll
    for(int g=0; g<8; ++g)
      *(uint4v*)(knd + srow*64 + ((scol + g*4) ^ sphi)) = pf[g];
    // ---- prefetch next round ----
    if(t < 3){
      #pragma unroll
      for(int g=0; g<8; ++g) pf[g] = *(const uint4v*)(kbt + (size_t)(t+1)*16384 + g*4);
    }

    // ---- QK: s1 rows rA-group, s2 rows rB-group ----
    float4v s1 = (float4v){0.f,0.f,0.f,0.f};
    float4v s2 = (float4v){0.f,0.f,0.f,0.f};
    #pragma unroll
    for(int s = 0; s < 2; ++s){
      const int c0 = s*32 + quad*8;
      uint4v w0 = *(const uint4v*)(knd + rowA*64 + ((c0    ) ^ phiA));
      uint4v w1 = *(const uint4v*)(knd + rowA*64 + ((c0 + 4) ^ phiA));
      uint4v u0 = *(const uint4v*)(knd + rowB*64 + ((c0    ) ^ phiB));
      uint4v u1 = *(const uint4v*)(knd + rowB*64 + ((c0 + 4) ^ phiB));
      bf16x8 a1h, a1l, a2h, a2l;
      #pragma unroll
      for(int j = 0; j < 4; ++j){
        a1h[j]   = (short)(w0[j] & 0xffffu);  a1l[j]   = (short)(w0[j] >> 16);
        a1h[j+4] = (short)(w1[j] & 0xffffu);  a1l[j+4] = (short)(w1[j] >> 16);
        a2h[j]   = (short)(u0[j] & 0xffffu);  a2l[j]   = (short)(u0[j] >> 16);
        a2h[j+4] = (short)(u1[j] & 0xffffu);  a2l[j+4] = (short)(u1[j] >> 16);
      }
      s1 = __builtin_amdgcn_mfma_f32_16x16x32_bf16(a1h, qh[s], s1, 0,0,0);
      s1 = __builtin_amdgcn_mfma_f32_16x16x32_bf16(a1l, qh[s], s1, 0,0,0);
      s1 = __builtin_amdgcn_mfma_f32_16x16x32_bf16(a1h, ql[s], s1, 0,0,0);
      s2 = __builtin_amdgcn_mfma_f32_16x16x32_bf16(a2h, qh[s], s2, 0,0,0);
      s2 = __builtin_amdgcn_mfma_f32_16x16x32_bf16(a2l, qh[s], s2, 0,0,0);
      s2 = __builtin_amdgcn_mfma_f32_16x16x32_bf16(a2h, ql[s], s2, 0,0,0);
    }

    // ---- exp + split P in registers (D-layout == PV A-layout) ----
    bf16x8 pa_h, pa_l;
    #pragma unroll
    for(int e = 0; e < 4; ++e){
      float v = __expf(s1[e]);
      lsum += v;
      unsigned int hh, ll;
      splitbf(v, hh, ll);
      pa_h[e] = (short)hh;
      pa_l[e] = (short)ll;
      float v2 = __expf(s2[e]);
      lsum += v2;
      splitbf(v2, hh, ll);
      pa_h[e+4] = (short)hh;
      pa_l[e+4] = (short)ll;
    }

    // ---- PV over wave's 32 rows (K=32), wave-local reads ----
    const int rb0 = wave*32 + quad*8;
    #pragma unroll
    for(int j = 0; j < 4; ++j){
      bf16x8 kbh, kbl;
      #pragma unroll
      for(int e = 0; e < 8; ++e){
        const int jx = ((e >> 2) ^ q1) & 1;
        unsigned int w = knd[(rb0 + e)*64 + ((j ^ jx) << 4) + (l16 ^ ((e & 3) << 2))];
        kbh[e] = (short)(w & 0xffffu);
        kbl[e] = (short)(w >> 16);
      }
      acc[j] = __builtin_amdgcn_mfma_f32_16x16x32_bf16(pa_h, kbh, acc[j], 0,0,0);
      acc[j] = __builtin_amdgcn_mfma_f32_16x16x32_bf16(pa_l, kbh, acc[j], 0,0,0);
      acc[j] = __builtin_amdgcn_mfma_f32_16x16x32_bf16(pa_h, kbl, acc[j], 0,0,0);
    }
  } // rounds

  // ---- block reduction + atomic partial accumulation ----
  __syncthreads();   // all waves done with knd tiles (accf aliases knd)
  lsum += __shfl_xor(lsum, 16);
  lsum += __shfl_xor(lsum, 32);
  if(quad == 0) lredf[wave*16 + l16] = lsum;
  #pragma unroll
  for(int j = 0; j < 4; ++j)
    #pragma unroll
    for(int r = 0; r < 4; ++r)
      accf[wave*1024 + (quad*4 + r)*64 + j*16 + l16] = acc[j][r];
  __syncthreads();
  #pragma unroll
  for(int k = 0; k < 2; ++k){
    const int i = tid + k*512;          // 0..1023
    float s = 0.f;
    #pragma unroll
    for(int w = 0; w < 8; ++w){ s += accf[w*1024 + i]; }
    atomicAdd(&gacc[(size_t)bh*1024 + i], s);
  }
  if(tid < 16){
    float lt = 0.f;
    #pragma unroll
    for(int w = 0; w < 8; ++w){ lt += lredf[w*16 + tid]; }
    atomicAdd(&glsum[bh*16 + tid], lt);
  }
}

// ---------------------------------------------------------------------------
// attn_reduce: q = acc/(1 + lsum); re-zero accumulators for next iteration.
// final=0: write qred[bh][l][64].  final=1: write qcur[b][l][768] (proj layout)
// ---------------------------------------------------------------------------
__global__ __launch_bounds__(256)
void attn_reduce_kernel(float* __restrict__ gacc, float* __restrict__ glsum,
                        float* __restrict__ qred, float* __restrict__ qcur,
                        int final){
  const int bh = blockIdx.x;            // 0..191
  const int b  = bh / 12, h = bh - b*12;
  #pragma unroll
  for(int k = 0; k < 4; ++k){
    const int i = threadIdx.x + k*256;  // 0..1023 : l=i>>6, d=i&63
    const int l = i >> 6, d = i & 63;
    const float s  = gacc[(size_t)bh*1024 + i];
    const float lt = 1.f + glsum[bh*16 + l];
    const float qv = s / lt;
    if(final) qcur[(size_t)(b*16 + l)*768 + h*64 + d] = qv;
    else      qred[(size_t)bh*1024 + i] = qv;
    gacc[(size_t)bh*1024 + i] = 0.f;    // ready for next iteration
  }
  if(threadIdx.x < 16) glsum[bh*16 + threadIdx.x] = 0.f;
}

// ---------------------------------------------------------------------------
// out[r][c] = sum_j inp[r][j]*W[c][j] (+bias). 4 rows x 256 cols per block.
// ---------------------------------------------------------------------------
__global__ __launch_bounds__(256)
void proj_kernel(const float* __restrict__ inp, const float* __restrict__ w,
                 const float* __restrict__ bias, float* __restrict__ out){
  __shared__ float rows[4*768];
  const int r0 = blockIdx.x*4;
  const int c  = blockIdx.y*256 + threadIdx.x;
  for(int j = threadIdx.x; j < 4*768; j += 256) rows[j] = inp[(size_t)r0*768 + j];
  __syncthreads();
  const float* wr = w + (size_t)c*768;
  float a0=0.f, a1=0.f, a2=0.f, a3=0.f;
  for(int j=0;j<768;j+=4){
    float4v w4 = *(const float4v*)(wr+j);
    float4v r0v = *(const float4v*)(rows+j);
    float4v r1v = *(const float4v*)(rows+768+j);
    float4v r2v = *(const float4v*)(rows+1536+j);
    float4v r3v = *(const float4v*)(rows+2304+j);
    #pragma unroll
    for(int e=0;e<4;e++){
      a0 += r0v[e]*w4[e]; a1 += r1v[e]*w4[e];
      a2 += r2v[e]*w4[e]; a3 += r3v[e]*w4[e];
    }
  }
  const float bb = bias ? bias[c] : 0.f;
  out[(size_t)(r0+0)*768 + c] = a0 + bb;
  out[(size_t)(r0+1)*768 + c] = a1 + bb;
  out[(size_t)(r0+2)*768 + c] = a2 + bb;
  out[(size_t)(r0+3)*768 + c] = a3 + bb;
}

// ---------------------------------------------------------------------------
extern "C" void kernel_launch(void* const* d_in, const int* in_sizes, int n_in,
                              void* d_out, int out_size, void* d_ws, size_t ws_size,
                              hipStream_t stream){
  const float* x     = (const float*)d_in[0];   // [16,4096,768]
  const float* query = (const float*)d_in[1];   // [1,16,768]
  const float* Wq    = (const float*)d_in[2];   // [768,768]
  const float* Wk    = (const float*)d_in[3];
  const float* Wv    = (const float*)d_in[4];
  const float* Wproj = (const float*)d_in[5];
  const float* bproj = (const float*)d_in[6];   // [768]
  float* out = (float*)d_out;                   // [16,16,768] fp32

  char* ws = (char*)d_ws;
  unsigned int*   khead = (unsigned int*)(ws);           // 201326592 B
  float*          qcur  = (float*)(ws + 201326592);      // 786432 B
  float*          q0    = (float*)(ws + 202113024);      // 49152 B
  char*           R     = ws + 202162176;                // 2359296 B region
  // gemm phase (R):
  unsigned short* wkh   = (unsigned short*)(R);
  unsigned short* wkl   = (unsigned short*)(R + 1179648);
  // attn phase (R, after gemm done): gacc | glsum contiguous, then qred
  float*          gacc  = (float*)(R);                   // 786432 B
  float*          glsum = (float*)(R + 786432);          // 12288 B
  float*          qred  = (float*)(R + 798720);          // 786432 B
  // proj phase (R, after attn done):
  float*          out1  = (float*)(R);                   // 786432 B

  cvt_planar_kernel<<<576, 256, 0, stream>>>(Wk, wkh, wkl);
  q0_kernel<<<48, 256, 0, stream>>>(query, Wq, q0);
  gemm_k_kernel<<<3072, 256, 0, stream>>>(x, wkh, wkl, khead);

  // zero gacc+glsum (contiguous 199680 floats) — overwrites wkh (gemm done)
  zero_kernel<<<390, 512, 0, stream>>>(gacc);

  for(int it = 0; it < 3; ++it){
    attn_part_kernel<<<768, 512, 0, stream>>>(khead, q0, qred, it == 0 ? 1 : 0,
                                              gacc, glsum);
    attn_reduce_kernel<<<192, 256, 0, stream>>>(gacc, glsum, qred, qcur,
                                                it == 2 ? 1 : 0);
  }

  proj_kernel<<<dim3(64, 3), 256, 0, stream>>>(qcur, Wv, nullptr, out1);
  proj_kernel<<<dim3(64, 3), 256, 0, stream>>>(out1, Wproj, bproj, out);
}

// Round 5
// 726.147 us; speedup vs baseline: 1.1156x; 1.1156x over previous
//
#include <hip/hip_runtime.h>

// ---------------------------------------------------------------------------
// HopfieldPooling on MI355X (gfx950)
//   k = x@Wk^T  (split-bf16 MFMA, 3-term; verified structure: single-buffer
//       LDS A-tile w/ on-stage convert + register prefetch, conflict-free
//       chunk-swizzled layout, B register-direct, XCD swizzle) -> packed
//       (hi|lo<<16) HEAD-MAJOR khead[b][h][n][64]
//   q0 = query@Wq^T (fp32)
//   attn3: ONE kernel, 192 blocks x 512 thr, all 3 Hopfield steps.
//       DEPTH-2 register prefetch (pfA/pfB, rounds unrolled x2): 16 KB/wave
//       in flight, counted vmcnt waits -> HBM latency hidden across 2 rounds.
//   out = (q@Wv^T)@Wproj^T + b  (fp32 vector)
// ---------------------------------------------------------------------------

typedef float  float4v  __attribute__((ext_vector_type(4)));
typedef short  short4v  __attribute__((ext_vector_type(4)));
typedef short  short8v  __attribute__((ext_vector_type(8)));
typedef unsigned int uint4v __attribute__((ext_vector_type(4)));
typedef short8v bf16x8;   // 8 bf16 = 4 VGPRs, MFMA A/B frag

// cheap split: hi = truncated bf16, lo = half-up-rounded bf16 of residual
__device__ __forceinline__ void splitbf(float v, unsigned int& hi, unsigned int& lo){
  unsigned int u = __float_as_uint(v);
  hi = u >> 16;
  float r = v - __uint_as_float(u & 0xffff0000u);
  lo = (__float_as_uint(r) + 0x8000u) >> 16;
}
// packed (hi | lo<<16)
__device__ __forceinline__ unsigned int packbf(float v){
  unsigned int u = __float_as_uint(v);
  float r = v - __uint_as_float(u & 0xffff0000u);
  return (u >> 16) | ((__float_as_uint(r) + 0x8000u) & 0xffff0000u);
}

// ---------------------------------------------------------------------------
// fp32 -> planar hi/lo bf16 (Wk 768x768)
// ---------------------------------------------------------------------------
__global__ __launch_bounds__(256)
void cvt_planar_kernel(const float* __restrict__ src, unsigned short* __restrict__ dh,
                       unsigned short* __restrict__ dl){
  size_t idx = (size_t)blockIdx.x*256 + threadIdx.x;
  float4v v = ((const float4v*)src)[idx];
  short4v h4, l4;
  #pragma unroll
  for(int e=0;e<4;e++){
    unsigned int hh, ll;
    splitbf(v[e], hh, ll);
    h4[e] = (short)hh;
    l4[e] = (short)ll;
  }
  ((short4v*)dh)[idx] = h4;
  ((short4v*)dl)[idx] = l4;
}

// ---------------------------------------------------------------------------
// q0[l][c] = sum_j query[l][j]*Wq[c][j]   (16x768, fp32)
// ---------------------------------------------------------------------------
__global__ __launch_bounds__(256)
void q0_kernel(const float* __restrict__ query, const float* __restrict__ wq,
               float* __restrict__ q0){
  int idx = blockIdx.x*256 + threadIdx.x;     // 12288
  int l = idx / 768, c = idx - l*768;
  const float* qr = query + l*768;
  const float* wr = wq + (size_t)c*768;
  float s = 0.f;
  for(int j=0;j<768;j+=4){
    float4v a  = *(const float4v*)(qr+j);
    float4v w4 = *(const float4v*)(wr+j);
    s += a[0]*w4[0]+a[1]*w4[1]+a[2]*w4[2]+a[3]*w4[3];
  }
  q0[idx] = s;
}

// ---------------------------------------------------------------------------
// k = x @ Wk^T.  (verified version, 277 us, VGPR 64)
//  - A tile in LDS as 16B chunks: chunk(row,c8) = row*4 + (c8 ^ ((row>>2)&3)).
//    Staging writes are stride-1 per quarter-wave (conflict-free); fragment
//    reads spread start-banks 2-way (free).
//  - Next K-step's x loaded into registers right after the 2nd barrier, so
//    HBM/L3 latency hides under the MFMA phase instead of the convert phase.
// ---------------------------------------------------------------------------
__global__ __launch_bounds__(256, 3)
void gemm_k_kernel(const float* __restrict__ x, const unsigned short* __restrict__ wh,
                   const unsigned short* __restrict__ wl, unsigned int* __restrict__ khead){
  __shared__ unsigned short Ah[512*8], Al[512*8];     // 8 KB each, chunk layout
  const int tid  = threadIdx.x;
  const int id   = blockIdx.x;          // 0..3071
  const int xcd  = id & 7, slot = id >> 3;
  const int bml  = slot / 6;            // 0..63
  const int bn   = slot - bml*6;        // 0..5
  const int bm   = xcd*64 + bml;        // 0..511
  const int wave = tid >> 6, lane = tid & 63, quad = lane >> 4, l16 = lane & 15;

  float4v acc[8][2];
  #pragma unroll
  for(int i=0;i<8;i++)
    #pragma unroll
    for(int j=0;j<2;j++) acc[i][j] = (float4v){0.f,0.f,0.f,0.f};

  const float* xA = x + (size_t)bm*128*768;
  const unsigned short* wbh = wh + (size_t)(bn*128 + wave*32 + l16)*768 + quad*8;
  const unsigned short* wbl = wl + (size_t)(bn*128 + wave*32 + l16)*768 + quad*8;

  // staging addressing: thread owns (row0,c8) and (row0+64,c8)
  const int row0 = tid >> 2, c8 = tid & 3;
  const int C0 = row0*4 + (c8 ^ ((row0 >> 2) & 3));   // == wave*64 + lane (stride-1)
  const int C1 = C0 + 256;                            // row0+64: >>2 adds 16 (mod4 = 0)
  const float* g0 = xA + (size_t)row0*768 + c8*8;
  const float* g1 = g0 + (size_t)64*768;
  // fragment-read chunk offset (+ i*64)
  const int crd = l16*4 + (quad ^ ((l16 >> 2) & 3));

  // prologue prefetch (k0 = 0)
  float4v p00 = *(const float4v*)(g0);
  float4v p01 = *(const float4v*)(g0 + 4);
  float4v p10 = *(const float4v*)(g1);
  float4v p11 = *(const float4v*)(g1 + 4);

  for(int k0=0;k0<768;k0+=32){
    bf16x8 b_h[2], b_l[2];
    #pragma unroll
    for(int j=0;j<2;j++){
      b_h[j] = *(const bf16x8*)(wbh + (size_t)j*16*768 + k0);
      b_l[j] = *(const bf16x8*)(wbl + (size_t)j*16*768 + k0);
    }
    __syncthreads();                      // LDS free (prev MFMA done)

    // convert prefetched regs -> LDS (pure VALU + 4 ds_writes)
    {
      short8v hv, lv;
      #pragma unroll
      for(int e=0;e<4;e++){
        unsigned int hh, ll;
        splitbf(p00[e], hh, ll); hv[e]   = (short)hh; lv[e]   = (short)ll;
        splitbf(p01[e], hh, ll); hv[e+4] = (short)hh; lv[e+4] = (short)ll;
      }
      *(short8v*)(Ah + C0*8) = hv;
      *(short8v*)(Al + C0*8) = lv;
      #pragma unroll
      for(int e=0;e<4;e++){
        unsigned int hh, ll;
        splitbf(p10[e], hh, ll); hv[e]   = (short)hh; lv[e]   = (short)ll;
        splitbf(p11[e], hh, ll); hv[e+4] = (short)hh; lv[e+4] = (short)ll;
      }
      *(short8v*)(Ah + C1*8) = hv;
      *(short8v*)(Al + C1*8) = lv;
    }
    __syncthreads();

    // issue next K-step's x loads NOW: in flight across the MFMA phase,
    // drained by the compiler's vmcnt(0) at the next barrier.
    if(k0 + 32 < 768){
      p00 = *(const float4v*)(g0 + k0 + 32);
      p01 = *(const float4v*)(g0 + k0 + 36);
      p10 = *(const float4v*)(g1 + k0 + 32);
      p11 = *(const float4v*)(g1 + k0 + 36);
    }

    #pragma unroll
    for(int i=0;i<8;i++){
      const unsigned short* ap = Ah + (size_t)(i*64 + crd)*8;
      const unsigned short* lp = Al + (size_t)(i*64 + crd)*8;
      bf16x8 a_h = *(const bf16x8*)ap;
      bf16x8 a_l = *(const bf16x8*)lp;
      #pragma unroll
      for(int j=0;j<2;j++){
        acc[i][j] = __builtin_amdgcn_mfma_f32_16x16x32_bf16(a_h, b_h[j], acc[i][j],0,0,0);
        acc[i][j] = __builtin_amdgcn_mfma_f32_16x16x32_bf16(a_l, b_h[j], acc[i][j],0,0,0);
        acc[i][j] = __builtin_amdgcn_mfma_f32_16x16x32_bf16(a_h, b_l[j], acc[i][j],0,0,0);
      }
    }
  }
  // epilogue: head-major packed store. Wave covers 32 cols within one head.
  const int b     = bm >> 5;
  const int Cbase = bn*128 + wave*32;
  const int h     = Cbase >> 6;
  const int dbase = Cbase & 63;        // 0 or 32
  const int nn0   = (bm & 31)*128;
  unsigned int* kout = khead + ((size_t)(b*12 + h)*4096 + nn0)*64 + dbase;
  #pragma unroll
  for(int i=0;i<8;i++)
    #pragma unroll
    for(int j=0;j<2;j++)
      #pragma unroll
      for(int r=0;r<4;r++)
        kout[(size_t)(i*16 + quad*4 + r)*64 + j*16 + l16] = packbf(acc[i][j][r]);
}

// ---------------------------------------------------------------------------
// attn3: one block per (b,h), 512 threads = 8 waves, 3 iterations in-kernel.
// Per round: wave stages ITS OWN 32 rows (global coalesced, swizzled LDS),
// QK (sigma-permuted A rows -> P lands in PV A-layout), exp, PV — all
// wave-local, NO barriers in the round loop. DEPTH-2 register prefetch:
// rounds unrolled x2 with static pfA/pfB; reloads issued every round so the
// compiler emits counted vmcnt(8) waits (2 rounds of latency budget).
// Iteration boundary: block reduction of acc/lsum through LDS + renorm q
// (softmax_1: 1 + sum). LDS swizzle: phi(r) = ((r&7)<<2) ^ ((r&8)<<1).
// ---------------------------------------------------------------------------
__global__ __launch_bounds__(512, 2)
void attn3_kernel(const unsigned int* __restrict__ khead,
                  const float* __restrict__ q0g, float* __restrict__ qcur){
  __shared__ unsigned int knd[256*64];            // 64 KB exactly
  float* accf  = (float*)knd;                     // [8][1024] at iter boundary
  float* lredf = (float*)knd + 8192;              // [8][16]
  float* qtmp  = (float*)knd + 8320;              // [16][64]

  const int tid  = threadIdx.x;
  const int bh   = blockIdx.x;
  const int b    = bh / 12;
  const int h    = bh - b*12;
  const int wave = tid >> 6, lane = tid & 63, quad = lane >> 4, l16 = lane & 15;

  const unsigned int* kb = khead + (size_t)(b*12 + h)*4096*64;
  // staging: thread owns tile row tid>>1, u32 half (tid&1)*32
  const int srow = tid >> 1, scol = (tid & 1)*32;
  const int sphi = ((srow & 7) << 2) ^ ((srow & 8) << 1);
  const unsigned int* kbt = kb + (size_t)srow*64 + scol;

  // QK addressing (sigma-permuted rows, wave-local)
  const int rowA = wave*32 + ((l16 >> 2) << 3) + (l16 & 3);
  const int rowB = rowA + 4;
  const int phiA = ((l16 & 3) << 2) ^ (((l16 >> 2) & 1) << 4);
  const int phiB = phiA ^ 16;
  const int q1   = quad & 1;

  // depth-2 prefetch: pfA = tile 0, pfB = tile 1
  uint4v pfA[8], pfB[8];
  #pragma unroll
  for(int g=0; g<8; ++g) pfA[g] = *(const uint4v*)(kbt + g*4);
  #pragma unroll
  for(int g=0; g<8; ++g) pfB[g] = *(const uint4v*)(kbt + 16384 + g*4);

  for(int iter = 0; iter < 3; ++iter){
    // ---- q fragments (scale 1/8 folded), split hi/lo; lane l16 = l ----
    const float* qrow = (iter == 0) ? (q0g + (size_t)l16*768 + h*64)
                                    : (qtmp + l16*64);
    bf16x8 qh[2], ql[2];
    #pragma unroll
    for(int s = 0; s < 2; ++s){
      float4v v0 = *(const float4v*)(qrow + s*32 + quad*8);
      float4v v1 = *(const float4v*)(qrow + s*32 + quad*8 + 4);
      #pragma unroll
      for(int e = 0; e < 8; ++e){
        float v = (e < 4 ? v0[e] : v1[e-4]) * 0.125f;
        unsigned int hh, ll;
        splitbf(v, hh, ll);
        qh[s][e] = (short)hh;
        ql[s][e] = (short)ll;
      }
    }
    __syncthreads();   // all waves done reading qtmp before LDS reuse

    float4v acc[4];
    #pragma unroll
    for(int j=0;j<4;j++) acc[j] = (float4v){0.f,0.f,0.f,0.f};
    float lsum = 0.f;

    // one round: QK (s1/s2), exp+split P, PV — reads wave-local LDS rows
    auto round_compute = [&](){
      float4v s1 = (float4v){0.f,0.f,0.f,0.f};
      float4v s2 = (float4v){0.f,0.f,0.f,0.f};
      #pragma unroll
      for(int s = 0; s < 2; ++s){
        const int c0 = s*32 + quad*8;
        uint4v w0 = *(const uint4v*)(knd + rowA*64 + ((c0    ) ^ phiA));
        uint4v w1 = *(const uint4v*)(knd + rowA*64 + ((c0 + 4) ^ phiA));
        uint4v u0 = *(const uint4v*)(knd + rowB*64 + ((c0    ) ^ phiB));
        uint4v u1 = *(const uint4v*)(knd + rowB*64 + ((c0 + 4) ^ phiB));
        bf16x8 a1h, a1l, a2h, a2l;
        #pragma unroll
        for(int j = 0; j < 4; ++j){
          a1h[j]   = (short)(w0[j] & 0xffffu);  a1l[j]   = (short)(w0[j] >> 16);
          a1h[j+4] = (short)(w1[j] & 0xffffu);  a1l[j+4] = (short)(w1[j] >> 16);
          a2h[j]   = (short)(u0[j] & 0xffffu);  a2l[j]   = (short)(u0[j] >> 16);
          a2h[j+4] = (short)(u1[j] & 0xffffu);  a2l[j+4] = (short)(u1[j] >> 16);
        }
        s1 = __builtin_amdgcn_mfma_f32_16x16x32_bf16(a1h, qh[s], s1, 0,0,0);
        s1 = __builtin_amdgcn_mfma_f32_16x16x32_bf16(a1l, qh[s], s1, 0,0,0);
        s1 = __builtin_amdgcn_mfma_f32_16x16x32_bf16(a1h, ql[s], s1, 0,0,0);
        s2 = __builtin_amdgcn_mfma_f32_16x16x32_bf16(a2h, qh[s], s2, 0,0,0);
        s2 = __builtin_amdgcn_mfma_f32_16x16x32_bf16(a2l, qh[s], s2, 0,0,0);
        s2 = __builtin_amdgcn_mfma_f32_16x16x32_bf16(a2h, ql[s], s2, 0,0,0);
      }

      bf16x8 pa_h, pa_l;
      #pragma unroll
      for(int e = 0; e < 4; ++e){
        float v = __expf(s1[e]);
        lsum += v;
        unsigned int hh, ll;
        splitbf(v, hh, ll);
        pa_h[e] = (short)hh;
        pa_l[e] = (short)ll;
        float v2 = __expf(s2[e]);
        lsum += v2;
        splitbf(v2, hh, ll);
        pa_h[e+4] = (short)hh;
        pa_l[e+4] = (short)ll;
      }

      const int rb0 = wave*32 + quad*8;
      #pragma unroll
      for(int j = 0; j < 4; ++j){
        bf16x8 kbh, kbl;
        #pragma unroll
        for(int e = 0; e < 8; ++e){
          const int jx = ((e >> 2) ^ q1) & 1;
          unsigned int w = knd[(rb0 + e)*64 + ((j ^ jx) << 4) + (l16 ^ ((e & 3) << 2))];
          kbh[e] = (short)(w & 0xffffu);
          kbl[e] = (short)(w >> 16);
        }
        acc[j] = __builtin_amdgcn_mfma_f32_16x16x32_bf16(pa_h, kbh, acc[j], 0,0,0);
        acc[j] = __builtin_amdgcn_mfma_f32_16x16x32_bf16(pa_l, kbh, acc[j], 0,0,0);
        acc[j] = __builtin_amdgcn_mfma_f32_16x16x32_bf16(pa_h, kbl, acc[j], 0,0,0);
      }
    };

    for(int tt = 0; tt < 8; ++tt){
      // ---- round 2*tt: stage pfA, reload pfA <- tile (2*tt+2)&15 ----
      #pragma unroll
      for(int g=0; g<8; ++g)
        *(uint4v*)(knd + srow*64 + ((scol + g*4) ^ sphi)) = pfA[g];
      {
        const int tn = (2*tt + 2) & 15;   // wraps to tile 0 for next iteration
        #pragma unroll
        for(int g=0; g<8; ++g) pfA[g] = *(const uint4v*)(kbt + (size_t)tn*16384 + g*4);
      }
      round_compute();

      // ---- round 2*tt+1: stage pfB, reload pfB <- tile (2*tt+3)&15 ----
      #pragma unroll
      for(int g=0; g<8; ++g)
        *(uint4v*)(knd + srow*64 + ((scol + g*4) ^ sphi)) = pfB[g];
      {
        const int tn = (2*tt + 3) & 15;   // wraps to tile 1 for next iteration
        #pragma unroll
        for(int g=0; g<8; ++g) pfB[g] = *(const uint4v*)(kbt + (size_t)tn*16384 + g*4);
      }
      round_compute();
    } // rounds

    // ---- iteration boundary: block reduction + renorm ----
    __syncthreads();   // all waves done with knd tiles
    lsum += __shfl_xor(lsum, 16);
    lsum += __shfl_xor(lsum, 32);
    if(quad == 0) lredf[wave*16 + l16] = lsum;
    #pragma unroll
    for(int j = 0; j < 4; ++j)
      #pragma unroll
      for(int r = 0; r < 4; ++r)
        accf[wave*1024 + (quad*4 + r)*64 + j*16 + l16] = acc[j][r];
    __syncthreads();
    #pragma unroll
    for(int k = 0; k < 2; ++k){
      const int i = tid + k*512;          // 0..1023 : l=i>>6, d=i&63
      const int l = i >> 6, d = i & 63;
      float s = 0.f, lt = 1.f;
      #pragma unroll
      for(int w = 0; w < 8; ++w){ s += accf[w*1024 + i]; }
      #pragma unroll
      for(int w = 0; w < 8; ++w){ lt += lredf[w*16 + l]; }
      const float qv = s / lt;
      if(iter < 2) qtmp[i] = qv;
      else qcur[(size_t)(b*16 + l)*768 + h*64 + d] = qv;
    }
    __syncthreads();   // qtmp visible to all waves before next frag build
  } // iterations
}

// ---------------------------------------------------------------------------
// out[r][c] = sum_j inp[r][j]*W[c][j] (+bias). 4 rows x 256 cols per block.
// ---------------------------------------------------------------------------
__global__ __launch_bounds__(256)
void proj_kernel(const float* __restrict__ inp, const float* __restrict__ w,
                 const float* __restrict__ bias, float* __restrict__ out){
  __shared__ float rows[4*768];
  const int r0 = blockIdx.x*4;
  const int c  = blockIdx.y*256 + threadIdx.x;
  for(int j = threadIdx.x; j < 4*768; j += 256) rows[j] = inp[(size_t)r0*768 + j];
  __syncthreads();
  const float* wr = w + (size_t)c*768;
  float a0=0.f, a1=0.f, a2=0.f, a3=0.f;
  for(int j=0;j<768;j+=4){
    float4v w4 = *(const float4v*)(wr+j);
    float4v r0v = *(const float4v*)(rows+j);
    float4v r1v = *(const float4v*)(rows+768+j);
    float4v r2v = *(const float4v*)(rows+1536+j);
    float4v r3v = *(const float4v*)(rows+2304+j);
    #pragma unroll
    for(int e=0;e<4;e++){
      a0 += r0v[e]*w4[e]; a1 += r1v[e]*w4[e];
      a2 += r2v[e]*w4[e]; a3 += r3v[e]*w4[e];
    }
  }
  const float bb = bias ? bias[c] : 0.f;
  out[(size_t)(r0+0)*768 + c] = a0 + bb;
  out[(size_t)(r0+1)*768 + c] = a1 + bb;
  out[(size_t)(r0+2)*768 + c] = a2 + bb;
  out[(size_t)(r0+3)*768 + c] = a3 + bb;
}

// ---------------------------------------------------------------------------
extern "C" void kernel_launch(void* const* d_in, const int* in_sizes, int n_in,
                              void* d_out, int out_size, void* d_ws, size_t ws_size,
                              hipStream_t stream){
  const float* x     = (const float*)d_in[0];   // [16,4096,768]
  const float* query = (const float*)d_in[1];   // [1,16,768]
  const float* Wq    = (const float*)d_in[2];   // [768,768]
  const float* Wk    = (const float*)d_in[3];
  const float* Wv    = (const float*)d_in[4];
  const float* Wproj = (const float*)d_in[5];
  const float* bproj = (const float*)d_in[6];   // [768]
  float* out = (float*)d_out;                   // [16,16,768] fp32

  char* ws = (char*)d_ws;
  unsigned int*   khead = (unsigned int*)(ws);           // 201326592 B
  float*          qcur  = (float*)(ws + 201326592);      // 786432 B
  float*          q0    = (float*)(ws + 202113024);      // 49152 B
  char*           R     = ws + 202162176;                // 2359296 B region
  unsigned short* wkh   = (unsigned short*)(R);          // gemm phase
  unsigned short* wkl   = (unsigned short*)(R + 1179648);
  float*          out1  = (float*)(R);                   // proj phase (alias)

  cvt_planar_kernel<<<576, 256, 0, stream>>>(Wk, wkh, wkl);
  q0_kernel<<<48, 256, 0, stream>>>(query, Wq, q0);
  gemm_k_kernel<<<3072, 256, 0, stream>>>(x, wkh, wkl, khead);

  attn3_kernel<<<192, 512, 0, stream>>>(khead, q0, qcur);

  proj_kernel<<<dim3(64, 3), 256, 0, stream>>>(qcur, Wv, nullptr, out1);
  proj_kernel<<<dim3(64, 3), 256, 0, stream>>>(out1, Wproj, bproj, out);
}

// Round 6
// 663.624 us; speedup vs baseline: 1.2208x; 1.0942x over previous
//
#include <hip/hip_runtime.h>

// ---------------------------------------------------------------------------
// HopfieldPooling on MI355X (gfx950)
//   k = x@Wk^T  (split-bf16 MFMA, 3-term; verified structure: single-buffer
//       LDS A-tile w/ on-stage convert + register prefetch, conflict-free
//       chunk-swizzled layout, B register-direct, XCD swizzle) -> packed
//       (hi|lo<<16) khead stored in PRE-SWIZZLED attn staging order:
//       khead[bh][t*16384 + row*64 + (d ^ phi(row))], phi(r)=((r&7)<<2)^((r&8)<<1)
//   q0 = query@Wq^T (fp32)
//   attn3: ONE kernel, 192 blocks x 512 thr, all 3 Hopfield steps.
//       Staging via global_load_lds (linear dest, pre-swizzled source, rule
//       21), double-buffered 2x64KB tile buffers, vmcnt-counted pipeline:
//       tile t+1 issued at top of round t -> full round of latency budget,
//       zero VGPR cost. Round loop stays wave-local, barrier-free.
//   out = (q@Wv^T)@Wproj^T + b  (fp32 vector)
// ---------------------------------------------------------------------------

typedef float  float4v  __attribute__((ext_vector_type(4)));
typedef short  short4v  __attribute__((ext_vector_type(4)));
typedef short  short8v  __attribute__((ext_vector_type(8)));
typedef unsigned int uint4v __attribute__((ext_vector_type(4)));
typedef short8v bf16x8;   // 8 bf16 = 4 VGPRs, MFMA A/B frag

// cheap split: hi = truncated bf16, lo = half-up-rounded bf16 of residual
__device__ __forceinline__ void splitbf(float v, unsigned int& hi, unsigned int& lo){
  unsigned int u = __float_as_uint(v);
  hi = u >> 16;
  float r = v - __uint_as_float(u & 0xffff0000u);
  lo = (__float_as_uint(r) + 0x8000u) >> 16;
}
// packed (hi | lo<<16)
__device__ __forceinline__ unsigned int packbf(float v){
  unsigned int u = __float_as_uint(v);
  float r = v - __uint_as_float(u & 0xffff0000u);
  return (u >> 16) | ((__float_as_uint(r) + 0x8000u) & 0xffff0000u);
}

// async 16B global -> LDS copy (lane l of the wave lands at lptr + l*16)
__device__ __forceinline__ void gll16(const unsigned int* g, unsigned int* l){
  __builtin_amdgcn_global_load_lds(
      (const __attribute__((address_space(1))) unsigned int*)g,
      (__attribute__((address_space(3))) unsigned int*)l, 16, 0, 0);
}

// ---------------------------------------------------------------------------
// fp32 -> planar hi/lo bf16 (Wk 768x768)
// ---------------------------------------------------------------------------
__global__ __launch_bounds__(256)
void cvt_planar_kernel(const float* __restrict__ src, unsigned short* __restrict__ dh,
                       unsigned short* __restrict__ dl){
  size_t idx = (size_t)blockIdx.x*256 + threadIdx.x;
  float4v v = ((const float4v*)src)[idx];
  short4v h4, l4;
  #pragma unroll
  for(int e=0;e<4;e++){
    unsigned int hh, ll;
    splitbf(v[e], hh, ll);
    h4[e] = (short)hh;
    l4[e] = (short)ll;
  }
  ((short4v*)dh)[idx] = h4;
  ((short4v*)dl)[idx] = l4;
}

// ---------------------------------------------------------------------------
// q0[l][c] = sum_j query[l][j]*Wq[c][j]   (16x768, fp32)
// ---------------------------------------------------------------------------
__global__ __launch_bounds__(256)
void q0_kernel(const float* __restrict__ query, const float* __restrict__ wq,
               float* __restrict__ q0){
  int idx = blockIdx.x*256 + threadIdx.x;     // 12288
  int l = idx / 768, c = idx - l*768;
  const float* qr = query + l*768;
  const float* wr = wq + (size_t)c*768;
  float s = 0.f;
  for(int j=0;j<768;j+=4){
    float4v a  = *(const float4v*)(qr+j);
    float4v w4 = *(const float4v*)(wr+j);
    s += a[0]*w4[0]+a[1]*w4[1]+a[2]*w4[2]+a[3]*w4[3];
  }
  q0[idx] = s;
}

// ---------------------------------------------------------------------------
// k = x @ Wk^T.  (verified compute, 277 us, VGPR 64)
//  - A tile in LDS as 16B chunks: chunk(row,c8) = row*4 + (c8 ^ ((row>>2)&3)).
//  - Next K-step's x loaded into registers right after the 2nd barrier.
//  - NEW epilogue: store khead in attn3's LDS-image order (pre-swizzled
//    source for global_load_lds): idx = t*16384 + row*64 + (d ^ phi(row)).
// ---------------------------------------------------------------------------
__global__ __launch_bounds__(256, 3)
void gemm_k_kernel(const float* __restrict__ x, const unsigned short* __restrict__ wh,
                   const unsigned short* __restrict__ wl, unsigned int* __restrict__ khead){
  __shared__ unsigned short Ah[512*8], Al[512*8];     // 8 KB each, chunk layout
  const int tid  = threadIdx.x;
  const int id   = blockIdx.x;          // 0..3071
  const int xcd  = id & 7, slot = id >> 3;
  const int bml  = slot / 6;            // 0..63
  const int bn   = slot - bml*6;        // 0..5
  const int bm   = xcd*64 + bml;        // 0..511
  const int wave = tid >> 6, lane = tid & 63, quad = lane >> 4, l16 = lane & 15;

  float4v acc[8][2];
  #pragma unroll
  for(int i=0;i<8;i++)
    #pragma unroll
    for(int j=0;j<2;j++) acc[i][j] = (float4v){0.f,0.f,0.f,0.f};

  const float* xA = x + (size_t)bm*128*768;
  const unsigned short* wbh = wh + (size_t)(bn*128 + wave*32 + l16)*768 + quad*8;
  const unsigned short* wbl = wl + (size_t)(bn*128 + wave*32 + l16)*768 + quad*8;

  // staging addressing: thread owns (row0,c8) and (row0+64,c8)
  const int row0 = tid >> 2, c8 = tid & 3;
  const int C0 = row0*4 + (c8 ^ ((row0 >> 2) & 3));   // == wave*64 + lane (stride-1)
  const int C1 = C0 + 256;                            // row0+64: >>2 adds 16 (mod4 = 0)
  const float* g0 = xA + (size_t)row0*768 + c8*8;
  const float* g1 = g0 + (size_t)64*768;
  // fragment-read chunk offset (+ i*64)
  const int crd = l16*4 + (quad ^ ((l16 >> 2) & 3));

  // prologue prefetch (k0 = 0)
  float4v p00 = *(const float4v*)(g0);
  float4v p01 = *(const float4v*)(g0 + 4);
  float4v p10 = *(const float4v*)(g1);
  float4v p11 = *(const float4v*)(g1 + 4);

  for(int k0=0;k0<768;k0+=32){
    bf16x8 b_h[2], b_l[2];
    #pragma unroll
    for(int j=0;j<2;j++){
      b_h[j] = *(const bf16x8*)(wbh + (size_t)j*16*768 + k0);
      b_l[j] = *(const bf16x8*)(wbl + (size_t)j*16*768 + k0);
    }
    __syncthreads();                      // LDS free (prev MFMA done)

    // convert prefetched regs -> LDS (pure VALU + 4 ds_writes)
    {
      short8v hv, lv;
      #pragma unroll
      for(int e=0;e<4;e++){
        unsigned int hh, ll;
        splitbf(p00[e], hh, ll); hv[e]   = (short)hh; lv[e]   = (short)ll;
        splitbf(p01[e], hh, ll); hv[e+4] = (short)hh; lv[e+4] = (short)ll;
      }
      *(short8v*)(Ah + C0*8) = hv;
      *(short8v*)(Al + C0*8) = lv;
      #pragma unroll
      for(int e=0;e<4;e++){
        unsigned int hh, ll;
        splitbf(p10[e], hh, ll); hv[e]   = (short)hh; lv[e]   = (short)ll;
        splitbf(p11[e], hh, ll); hv[e+4] = (short)hh; lv[e+4] = (short)ll;
      }
      *(short8v*)(Ah + C1*8) = hv;
      *(short8v*)(Al + C1*8) = lv;
    }
    __syncthreads();

    // issue next K-step's x loads NOW: in flight across the MFMA phase,
    // drained by the compiler's vmcnt(0) at the next barrier.
    if(k0 + 32 < 768){
      p00 = *(const float4v*)(g0 + k0 + 32);
      p01 = *(const float4v*)(g0 + k0 + 36);
      p10 = *(const float4v*)(g1 + k0 + 32);
      p11 = *(const float4v*)(g1 + k0 + 36);
    }

    #pragma unroll
    for(int i=0;i<8;i++){
      const unsigned short* ap = Ah + (size_t)(i*64 + crd)*8;
      const unsigned short* lp = Al + (size_t)(i*64 + crd)*8;
      bf16x8 a_h = *(const bf16x8*)ap;
      bf16x8 a_l = *(const bf16x8*)lp;
      #pragma unroll
      for(int j=0;j<2;j++){
        acc[i][j] = __builtin_amdgcn_mfma_f32_16x16x32_bf16(a_h, b_h[j], acc[i][j],0,0,0);
        acc[i][j] = __builtin_amdgcn_mfma_f32_16x16x32_bf16(a_l, b_h[j], acc[i][j],0,0,0);
        acc[i][j] = __builtin_amdgcn_mfma_f32_16x16x32_bf16(a_h, b_l[j], acc[i][j],0,0,0);
      }
    }
  }
  // epilogue: packed store in attn3 staging order.
  // element (n, d) of head (b,h):  t = n>>8, row = n&255,
  //   idx = t*16384 + row*64 + (d ^ phi(row)),  phi(r)=((r&7)<<2)^((r&8)<<1)
  const int b     = bm >> 5;
  const int Cbase = bn*128 + wave*32;
  const int h     = Cbase >> 6;
  const int dbase = Cbase & 63;        // 0 or 32
  const int nn0   = (bm & 31)*128;
  unsigned int* kout = khead + (size_t)(b*12 + h)*262144;
  #pragma unroll
  for(int i=0;i<8;i++){
    #pragma unroll
    for(int r=0;r<4;r++){
      const int n   = nn0 + i*16 + quad*4 + r;
      const int row = n & 255, t = n >> 8;
      const int ph  = ((row & 7) << 2) ^ ((row & 8) << 1);
      unsigned int* kr = kout + (size_t)t*16384 + row*64;
      #pragma unroll
      for(int j=0;j<2;j++)
        kr[(dbase + j*16 + l16) ^ ph] = packbf(acc[i][j][r]);
    }
  }
}

// ---------------------------------------------------------------------------
// attn3: one block per (b,h), 512 threads = 8 waves, 3 iterations in-kernel.
// Staging: global_load_lds, 8x1KB per wave per round, into double-buffered
// 64KB tile buffers (128 KB LDS). khead is pre-swizzled, so linear LDS dest
// reproduces the swizzled image; all QK/PV addressing identical to the
// verified kernel. Round t: wait vmcnt(0) (tile t landed), issue tile t+1
// into the other buffer, compute tile t — wave-local, barrier-free.
// Iteration boundary: block reduction via scratch placed INSIDE buf1 (the
// cross-boundary prefetch targets buf0, no collision) + renorm q
// (softmax_1: 1 + sum).
// ---------------------------------------------------------------------------
__global__ __launch_bounds__(512, 2)
void attn3_kernel(const unsigned int* __restrict__ khead,
                  const float* __restrict__ q0g, float* __restrict__ qcur){
  __shared__ unsigned int knd[2*16384];           // 128 KB: buf0 | buf1
  // boundary scratch lives in BUF1 (in-flight boundary prefetch -> buf0)
  float* accf  = (float*)(knd + 16384);           // [8][1024]
  float* lredf = (float*)(knd + 16384) + 8192;    // [8][16]
  float* qtmp  = (float*)(knd + 16384) + 8320;    // [16][64]

  const int tid  = threadIdx.x;
  const int bh   = blockIdx.x;
  const int b    = bh / 12;
  const int h    = bh - b*12;
  const int wave = tid >> 6, lane = tid & 63, quad = lane >> 4, l16 = lane & 15;

  const unsigned int* kg = khead + (size_t)bh*262144;     // 16 tiles x 16384 u32
  const unsigned int* kwv = kg + wave*2048 + lane*4;      // per-lane 16B source
  unsigned int* lwv = knd + wave*2048;                    // wave-uniform LDS dest

  // QK addressing (sigma-permuted rows, wave-local) — unchanged
  const int rowA = wave*32 + ((l16 >> 2) << 3) + (l16 & 3);
  const int rowB = rowA + 4;
  const int phiA = ((l16 & 3) << 2) ^ (((l16 >> 2) & 1) << 4);
  const int phiB = phiA ^ 16;
  const int q1   = quad & 1;

  // prologue: issue tile 0 -> buf0
  #pragma unroll
  for(int g=0; g<8; ++g) gll16(kwv + g*256, lwv + g*256);

  for(int iter = 0; iter < 3; ++iter){
    // ---- q fragments (scale 1/8 folded), split hi/lo; lane l16 = l ----
    const float* qrow = (iter == 0) ? (q0g + (size_t)l16*768 + h*64)
                                    : (qtmp + l16*64);
    bf16x8 qh[2], ql[2];
    #pragma unroll
    for(int s = 0; s < 2; ++s){
      float4v v0 = *(const float4v*)(qrow + s*32 + quad*8);
      float4v v1 = *(const float4v*)(qrow + s*32 + quad*8 + 4);
      #pragma unroll
      for(int e = 0; e < 8; ++e){
        float v = (e < 4 ? v0[e] : v1[e-4]) * 0.125f;
        unsigned int hh, ll;
        splitbf(v, hh, ll);
        qh[s][e] = (short)hh;
        ql[s][e] = (short)ll;
      }
    }
    __syncthreads();   // all waves done with qtmp before buf1 gets tile 1

    float4v acc[4];
    #pragma unroll
    for(int j=0;j<4;j++) acc[j] = (float4v){0.f,0.f,0.f,0.f};
    float lsum = 0.f;

    for(int t = 0; t < 16; ++t){
      const unsigned int* kcur = knd + ((t & 1) << 14);   // current tile buffer

      // tile t's loads are the only outstanding vmem -> counted wait
      asm volatile("s_waitcnt vmcnt(0)" ::: "memory");
      __builtin_amdgcn_sched_barrier(0);

      // issue tile t+1 into the other buffer (wraps to tile 0 across iters)
      if(!(iter == 2 && t == 15)){
        const int tn = (t + 1) & 15;
        const unsigned int* gsrc = kwv + (size_t)tn*16384;
        unsigned int* ldst = lwv + (((t + 1) & 1) << 14);
        #pragma unroll
        for(int g=0; g<8; ++g) gll16(gsrc + g*256, ldst + g*256);
      }

      // ---- QK: s1 rows rA-group, s2 rows rB-group ----
      float4v s1 = (float4v){0.f,0.f,0.f,0.f};
      float4v s2 = (float4v){0.f,0.f,0.f,0.f};
      #pragma unroll
      for(int s = 0; s < 2; ++s){
        const int c0 = s*32 + quad*8;
        uint4v w0 = *(const uint4v*)(kcur + rowA*64 + ((c0    ) ^ phiA));
        uint4v w1 = *(const uint4v*)(kcur + rowA*64 + ((c0 + 4) ^ phiA));
        uint4v u0 = *(const uint4v*)(kcur + rowB*64 + ((c0    ) ^ phiB));
        uint4v u1 = *(const uint4v*)(kcur + rowB*64 + ((c0 + 4) ^ phiB));
        bf16x8 a1h, a1l, a2h, a2l;
        #pragma unroll
        for(int j = 0; j < 4; ++j){
          a1h[j]   = (short)(w0[j] & 0xffffu);  a1l[j]   = (short)(w0[j] >> 16);
          a1h[j+4] = (short)(w1[j] & 0xffffu);  a1l[j+4] = (short)(w1[j] >> 16);
          a2h[j]   = (short)(u0[j] & 0xffffu);  a2l[j]   = (short)(u0[j] >> 16);
          a2h[j+4] = (short)(u1[j] & 0xffffu);  a2l[j+4] = (short)(u1[j] >> 16);
        }
        s1 = __builtin_amdgcn_mfma_f32_16x16x32_bf16(a1h, qh[s], s1, 0,0,0);
        s1 = __builtin_amdgcn_mfma_f32_16x16x32_bf16(a1l, qh[s], s1, 0,0,0);
        s1 = __builtin_amdgcn_mfma_f32_16x16x32_bf16(a1h, ql[s], s1, 0,0,0);
        s2 = __builtin_amdgcn_mfma_f32_16x16x32_bf16(a2h, qh[s], s2, 0,0,0);
        s2 = __builtin_amdgcn_mfma_f32_16x16x32_bf16(a2l, qh[s], s2, 0,0,0);
        s2 = __builtin_amdgcn_mfma_f32_16x16x32_bf16(a2h, ql[s], s2, 0,0,0);
      }

      // ---- exp + split P in registers (D-layout == PV A-layout) ----
      bf16x8 pa_h, pa_l;
      #pragma unroll
      for(int e = 0; e < 4; ++e){
        float v = __expf(s1[e]);
        lsum += v;
        unsigned int hh, ll;
        splitbf(v, hh, ll);
        pa_h[e] = (short)hh;
        pa_l[e] = (short)ll;
        float v2 = __expf(s2[e]);
        lsum += v2;
        splitbf(v2, hh, ll);
        pa_h[e+4] = (short)hh;
        pa_l[e+4] = (short)ll;
      }

      // ---- PV over wave's 32 rows (K=32), wave-local reads ----
      const int rb0 = wave*32 + quad*8;
      #pragma unroll
      for(int j = 0; j < 4; ++j){
        bf16x8 kbh, kbl;
        #pragma unroll
        for(int e = 0; e < 8; ++e){
          const int jx = ((e >> 2) ^ q1) & 1;
          unsigned int w = kcur[(rb0 + e)*64 + ((j ^ jx) << 4) + (l16 ^ ((e & 3) << 2))];
          kbh[e] = (short)(w & 0xffffu);
          kbl[e] = (short)(w >> 16);
        }
        acc[j] = __builtin_amdgcn_mfma_f32_16x16x32_bf16(pa_h, kbh, acc[j], 0,0,0);
        acc[j] = __builtin_amdgcn_mfma_f32_16x16x32_bf16(pa_l, kbh, acc[j], 0,0,0);
        acc[j] = __builtin_amdgcn_mfma_f32_16x16x32_bf16(pa_h, kbl, acc[j], 0,0,0);
      }
    } // rounds

    // ---- iteration boundary: block reduction + renorm ----
    __syncthreads();   // all waves done with buf1 (scratch region) tiles
    lsum += __shfl_xor(lsum, 16);
    lsum += __shfl_xor(lsum, 32);
    if(quad == 0) lredf[wave*16 + l16] = lsum;
    #pragma unroll
    for(int j = 0; j < 4; ++j)
      #pragma unroll
      for(int r = 0; r < 4; ++r)
        accf[wave*1024 + (quad*4 + r)*64 + j*16 + l16] = acc[j][r];
    __syncthreads();
    #pragma unroll
    for(int k = 0; k < 2; ++k){
      const int i = tid + k*512;          // 0..1023 : l=i>>6, d=i&63
      const int l = i >> 6, d = i & 63;
      float s = 0.f, lt = 1.f;
      #pragma unroll
      for(int w = 0; w < 8; ++w){ s += accf[w*1024 + i]; }
      #pragma unroll
      for(int w = 0; w < 8; ++w){ lt += lredf[w*16 + l]; }
      const float qv = s / lt;
      if(iter < 2) qtmp[i] = qv;
      else qcur[(size_t)(b*16 + l)*768 + h*64 + d] = qv;
    }
    __syncthreads();   // qtmp visible to all waves before next frag build
  } // iterations
}

// ---------------------------------------------------------------------------
// out[r][c] = sum_j inp[r][j]*W[c][j] (+bias). 4 rows x 256 cols per block.
// ---------------------------------------------------------------------------
__global__ __launch_bounds__(256)
void proj_kernel(const float* __restrict__ inp, const float* __restrict__ w,
                 const float* __restrict__ bias, float* __restrict__ out){
  __shared__ float rows[4*768];
  const int r0 = blockIdx.x*4;
  const int c  = blockIdx.y*256 + threadIdx.x;
  for(int j = threadIdx.x; j < 4*768; j += 256) rows[j] = inp[(size_t)r0*768 + j];
  __syncthreads();
  const float* wr = w + (size_t)c*768;
  float a0=0.f, a1=0.f, a2=0.f, a3=0.f;
  for(int j=0;j<768;j+=4){
    float4v w4 = *(const float4v*)(wr+j);
    float4v r0v = *(const float4v*)(rows+j);
    float4v r1v = *(const float4v*)(rows+768+j);
    float4v r2v = *(const float4v*)(rows+1536+j);
    float4v r3v = *(const float4v*)(rows+2304+j);
    #pragma unroll
    for(int e=0;e<4;e++){
      a0 += r0v[e]*w4[e]; a1 += r1v[e]*w4[e];
      a2 += r2v[e]*w4[e]; a3 += r3v[e]*w4[e];
    }
  }
  const float bb = bias ? bias[c] : 0.f;
  out[(size_t)(r0+0)*768 + c] = a0 + bb;
  out[(size_t)(r0+1)*768 + c] = a1 + bb;
  out[(size_t)(r0+2)*768 + c] = a2 + bb;
  out[(size_t)(r0+3)*768 + c] = a3 + bb;
}

// ---------------------------------------------------------------------------
extern "C" void kernel_launch(void* const* d_in, const int* in_sizes, int n_in,
                              void* d_out, int out_size, void* d_ws, size_t ws_size,
                              hipStream_t stream){
  const float* x     = (const float*)d_in[0];   // [16,4096,768]
  const float* query = (const float*)d_in[1];   // [1,16,768]
  const float* Wq    = (const float*)d_in[2];   // [768,768]
  const float* Wk    = (const float*)d_in[3];
  const float* Wv    = (const float*)d_in[4];
  const float* Wproj = (const float*)d_in[5];
  const float* bproj = (const float*)d_in[6];   // [768]
  float* out = (float*)d_out;                   // [16,16,768] fp32

  char* ws = (char*)d_ws;
  unsigned int*   khead = (unsigned int*)(ws);           // 201326592 B
  float*          qcur  = (float*)(ws + 201326592);      // 786432 B
  float*          q0    = (float*)(ws + 202113024);      // 49152 B
  char*           R     = ws + 202162176;                // 2359296 B region
  unsigned short* wkh   = (unsigned short*)(R);          // gemm phase
  unsigned short* wkl   = (unsigned short*)(R + 1179648);
  float*          out1  = (float*)(R);                   // proj phase (alias)

  cvt_planar_kernel<<<576, 256, 0, stream>>>(Wk, wkh, wkl);
  q0_kernel<<<48, 256, 0, stream>>>(query, Wq, q0);
  gemm_k_kernel<<<3072, 256, 0, stream>>>(x, wkh, wkl, khead);

  attn3_kernel<<<192, 512, 0, stream>>>(khead, q0, qcur);

  proj_kernel<<<dim3(64, 3), 256, 0, stream>>>(qcur, Wv, nullptr, out1);
  proj_kernel<<<dim3(64, 3), 256, 0, stream>>>(out1, Wproj, bproj, out);
}

// Round 8
// 661.573 us; speedup vs baseline: 1.2245x; 1.0031x over previous
//
#include <hip/hip_runtime.h>

// ---------------------------------------------------------------------------
// HopfieldPooling on MI355X (gfx950)
//   k = x@Wk^T  (split-bf16 MFMA, 3-term; verified structure: single-buffer
//       LDS A-tile w/ on-stage convert + register prefetch, conflict-free
//       chunk-swizzled layout, B register-direct, XCD swizzle) -> packed
//       (hi|lo<<16) khead stored in PRE-SWIZZLED attn staging order:
//       khead[bh][t*16384 + row*64 + (d ^ phi(row))], phi(r)=((r&7)<<2)^((r&8)<<1)
//   prep = Wk planarization + q0 = query@Wq^T fused (block-role split)
//   attn3: ONE kernel, 192 blocks x 512 thr, all 3 Hopfield steps.
//       Staging via global_load_lds (linear dest, pre-swizzled source),
//       double-buffered 2x64KB tile buffers. ISSUE-FIRST + COUNTED WAIT:
//       round t issues tile t+1's 8 loads, then s_waitcnt vmcnt(8) (waits
//       only tile t's 8 oldest; in-order vmem retirement), so wait-stall
//       time overlaps the next tile's HBM latency.
//   out = (q@Wv^T)@Wproj^T + b  (fp32 vector)
// ---------------------------------------------------------------------------

typedef float  float4v  __attribute__((ext_vector_type(4)));
typedef short  short4v  __attribute__((ext_vector_type(4)));
typedef short  short8v  __attribute__((ext_vector_type(8)));
typedef unsigned int uint4v __attribute__((ext_vector_type(4)));
typedef short8v bf16x8;   // 8 bf16 = 4 VGPRs, MFMA A/B frag

// cheap split: hi = truncated bf16, lo = half-up-rounded bf16 of residual
__device__ __forceinline__ void splitbf(float v, unsigned int& hi, unsigned int& lo){
  unsigned int u = __float_as_uint(v);
  hi = u >> 16;
  float r = v - __uint_as_float(u & 0xffff0000u);
  lo = (__float_as_uint(r) + 0x8000u) >> 16;
}
// packed (hi | lo<<16)
__device__ __forceinline__ unsigned int packbf(float v){
  unsigned int u = __float_as_uint(v);
  float r = v - __uint_as_float(u & 0xffff0000u);
  return (u >> 16) | ((__float_as_uint(r) + 0x8000u) & 0xffff0000u);
}

// async 16B global -> LDS copy (lane l of the wave lands at lptr + l*16)
__device__ __forceinline__ void gll16(const unsigned int* g, unsigned int* l){
  __builtin_amdgcn_global_load_lds(
      (const __attribute__((address_space(1))) unsigned int*)g,
      (__attribute__((address_space(3))) unsigned int*)l, 16, 0, 0);
}

// ---------------------------------------------------------------------------
// prep: blocks 0..575 = Wk fp32 -> planar hi/lo bf16; blocks 576..623 = q0.
// ---------------------------------------------------------------------------
__global__ __launch_bounds__(256)
void prep_kernel(const float* __restrict__ wk, unsigned short* __restrict__ dh,
                 unsigned short* __restrict__ dl,
                 const float* __restrict__ query, const float* __restrict__ wq,
                 float* __restrict__ q0){
  if(blockIdx.x < 576){
    size_t idx = (size_t)blockIdx.x*256 + threadIdx.x;
    float4v v = ((const float4v*)wk)[idx];
    short4v h4, l4;
    #pragma unroll
    for(int e=0;e<4;e++){
      unsigned int hh, ll;
      splitbf(v[e], hh, ll);
      h4[e] = (short)hh;
      l4[e] = (short)ll;
    }
    ((short4v*)dh)[idx] = h4;
    ((short4v*)dl)[idx] = l4;
  } else {
    int idx = (blockIdx.x - 576)*256 + threadIdx.x;   // 12288
    int l = idx / 768, c = idx - l*768;
    const float* qr = query + l*768;
    const float* wr = wq + (size_t)c*768;
    float s = 0.f;
    for(int j=0;j<768;j+=4){
      float4v a  = *(const float4v*)(qr+j);
      float4v w4 = *(const float4v*)(wr+j);
      s += a[0]*w4[0]+a[1]*w4[1]+a[2]*w4[2]+a[3]*w4[3];
    }
    q0[idx] = s;
  }
}

// ---------------------------------------------------------------------------
// k = x @ Wk^T.  (verified compute, 277 us, VGPR 64)
//  - A tile in LDS as 16B chunks: chunk(row,c8) = row*4 + (c8 ^ ((row>>2)&3)).
//  - Next K-step's x loaded into registers right after the 2nd barrier.
//  - Epilogue: store khead in attn3's LDS-image order (pre-swizzled source
//    for global_load_lds): idx = t*16384 + row*64 + (d ^ phi(row)).
// ---------------------------------------------------------------------------
__global__ __launch_bounds__(256, 3)
void gemm_k_kernel(const float* __restrict__ x, const unsigned short* __restrict__ wh,
                   const unsigned short* __restrict__ wl, unsigned int* __restrict__ khead){
  __shared__ unsigned short Ah[512*8], Al[512*8];     // 8 KB each, chunk layout
  const int tid  = threadIdx.x;
  const int id   = blockIdx.x;          // 0..3071
  const int xcd  = id & 7, slot = id >> 3;
  const int bml  = slot / 6;            // 0..63
  const int bn   = slot - bml*6;        // 0..5
  const int bm   = xcd*64 + bml;        // 0..511
  const int wave = tid >> 6, lane = tid & 63, quad = lane >> 4, l16 = lane & 15;

  float4v acc[8][2];
  #pragma unroll
  for(int i=0;i<8;i++)
    #pragma unroll
    for(int j=0;j<2;j++) acc[i][j] = (float4v){0.f,0.f,0.f,0.f};

  const float* xA = x + (size_t)bm*128*768;
  const unsigned short* wbh = wh + (size_t)(bn*128 + wave*32 + l16)*768 + quad*8;
  const unsigned short* wbl = wl + (size_t)(bn*128 + wave*32 + l16)*768 + quad*8;

  // staging addressing: thread owns (row0,c8) and (row0+64,c8)
  const int row0 = tid >> 2, c8 = tid & 3;
  const int C0 = row0*4 + (c8 ^ ((row0 >> 2) & 3));   // == wave*64 + lane (stride-1)
  const int C1 = C0 + 256;                            // row0+64: >>2 adds 16 (mod4 = 0)
  const float* g0 = xA + (size_t)row0*768 + c8*8;
  const float* g1 = g0 + (size_t)64*768;
  // fragment-read chunk offset (+ i*64)
  const int crd = l16*4 + (quad ^ ((l16 >> 2) & 3));

  // prologue prefetch (k0 = 0)
  float4v p00 = *(const float4v*)(g0);
  float4v p01 = *(const float4v*)(g0 + 4);
  float4v p10 = *(const float4v*)(g1);
  float4v p11 = *(const float4v*)(g1 + 4);

  for(int k0=0;k0<768;k0+=32){
    bf16x8 b_h[2], b_l[2];
    #pragma unroll
    for(int j=0;j<2;j++){
      b_h[j] = *(const bf16x8*)(wbh + (size_t)j*16*768 + k0);
      b_l[j] = *(const bf16x8*)(wbl + (size_t)j*16*768 + k0);
    }
    __syncthreads();                      // LDS free (prev MFMA done)

    // convert prefetched regs -> LDS (pure VALU + 4 ds_writes)
    {
      short8v hv, lv;
      #pragma unroll
      for(int e=0;e<4;e++){
        unsigned int hh, ll;
        splitbf(p00[e], hh, ll); hv[e]   = (short)hh; lv[e]   = (short)ll;
        splitbf(p01[e], hh, ll); hv[e+4] = (short)hh; lv[e+4] = (short)ll;
      }
      *(short8v*)(Ah + C0*8) = hv;
      *(short8v*)(Al + C0*8) = lv;
      #pragma unroll
      for(int e=0;e<4;e++){
        unsigned int hh, ll;
        splitbf(p10[e], hh, ll); hv[e]   = (short)hh; lv[e]   = (short)ll;
        splitbf(p11[e], hh, ll); hv[e+4] = (short)hh; lv[e+4] = (short)ll;
      }
      *(short8v*)(Ah + C1*8) = hv;
      *(short8v*)(Al + C1*8) = lv;
    }
    __syncthreads();

    // issue next K-step's x loads NOW: in flight across the MFMA phase,
    // drained by the compiler's vmcnt(0) at the next barrier.
    if(k0 + 32 < 768){
      p00 = *(const float4v*)(g0 + k0 + 32);
      p01 = *(const float4v*)(g0 + k0 + 36);
      p10 = *(const float4v*)(g1 + k0 + 32);
      p11 = *(const float4v*)(g1 + k0 + 36);
    }

    #pragma unroll
    for(int i=0;i<8;i++){
      const unsigned short* ap = Ah + (size_t)(i*64 + crd)*8;
      const unsigned short* lp = Al + (size_t)(i*64 + crd)*8;
      bf16x8 a_h = *(const bf16x8*)ap;
      bf16x8 a_l = *(const bf16x8*)lp;
      #pragma unroll
      for(int j=0;j<2;j++){
        acc[i][j] = __builtin_amdgcn_mfma_f32_16x16x32_bf16(a_h, b_h[j], acc[i][j],0,0,0);
        acc[i][j] = __builtin_amdgcn_mfma_f32_16x16x32_bf16(a_l, b_h[j], acc[i][j],0,0,0);
        acc[i][j] = __builtin_amdgcn_mfma_f32_16x16x32_bf16(a_h, b_l[j], acc[i][j],0,0,0);
      }
    }
  }
  // epilogue: packed store in attn3 staging order.
  // element (n, d) of head (b,h):  t = n>>8, row = n&255,
  //   idx = t*16384 + row*64 + (d ^ phi(row)),  phi(r)=((r&7)<<2)^((r&8)<<1)
  const int b     = bm >> 5;
  const int Cbase = bn*128 + wave*32;
  const int h     = Cbase >> 6;
  const int dbase = Cbase & 63;        // 0 or 32
  const int nn0   = (bm & 31)*128;
  unsigned int* kout = khead + (size_t)(b*12 + h)*262144;
  #pragma unroll
  for(int i=0;i<8;i++){
    #pragma unroll
    for(int r=0;r<4;r++){
      const int n   = nn0 + i*16 + quad*4 + r;
      const int row = n & 255, t = n >> 8;
      const int ph  = ((row & 7) << 2) ^ ((row & 8) << 1);
      unsigned int* kr = kout + (size_t)t*16384 + row*64;
      #pragma unroll
      for(int j=0;j<2;j++)
        kr[(dbase + j*16 + l16) ^ ph] = packbf(acc[i][j][r]);
    }
  }
}

// ---------------------------------------------------------------------------
// attn3: one block per (b,h), 512 threads = 8 waves, 3 iterations in-kernel.
// Staging: global_load_lds into double-buffered 64KB tile buffers. Round t:
// ISSUE tile t+1 (8 gll), then s_waitcnt vmcnt(8) — waits only the 8 oldest
// (= tile t) while t+1's loads ride across the wait. Compute is wave-local,
// barrier-free. Iteration boundary: block reduction via scratch in buf1
// (cross-boundary prefetch targets buf0) + renorm q (softmax_1: 1 + sum).
// ---------------------------------------------------------------------------
__global__ __launch_bounds__(512, 2)
void attn3_kernel(const unsigned int* __restrict__ khead,
                  const float* __restrict__ q0g, float* __restrict__ qcur){
  __shared__ unsigned int knd[2*16384];           // 128 KB: buf0 | buf1
  // boundary scratch lives in BUF1 (in-flight boundary prefetch -> buf0)
  float* accf  = (float*)(knd + 16384);           // [8][1024]
  float* lredf = (float*)(knd + 16384) + 8192;    // [8][16]
  float* qtmp  = (float*)(knd + 16384) + 8320;    // [16][64]

  const int tid  = threadIdx.x;
  const int bh   = blockIdx.x;
  const int b    = bh / 12;
  const int h    = bh - b*12;
  const int wave = tid >> 6, lane = tid & 63, quad = lane >> 4, l16 = lane & 15;

  const unsigned int* kg = khead + (size_t)bh*262144;     // 16 tiles x 16384 u32
  const unsigned int* kwv = kg + wave*2048 + lane*4;      // per-lane 16B source
  unsigned int* lwv = knd + wave*2048;                    // wave-uniform LDS dest

  // QK addressing (sigma-permuted rows, wave-local) — unchanged
  const int rowA = wave*32 + ((l16 >> 2) << 3) + (l16 & 3);
  const int rowB = rowA + 4;
  const int phiA = ((l16 & 3) << 2) ^ (((l16 >> 2) & 1) << 4);
  const int phiB = phiA ^ 16;
  const int q1   = quad & 1;

  // prologue: issue tile 0 -> buf0
  #pragma unroll
  for(int g=0; g<8; ++g) gll16(kwv + g*256, lwv + g*256);

  for(int iter = 0; iter < 3; ++iter){
    // ---- q fragments (scale 1/8 folded), split hi/lo; lane l16 = l ----
    const float* qrow = (iter == 0) ? (q0g + (size_t)l16*768 + h*64)
                                    : (qtmp + l16*64);
    bf16x8 qh[2], ql[2];
    #pragma unroll
    for(int s = 0; s < 2; ++s){
      float4v v0 = *(const float4v*)(qrow + s*32 + quad*8);
      float4v v1 = *(const float4v*)(qrow + s*32 + quad*8 + 4);
      #pragma unroll
      for(int e = 0; e < 8; ++e){
        float v = (e < 4 ? v0[e] : v1[e-4]) * 0.125f;
        unsigned int hh, ll;
        splitbf(v, hh, ll);
        qh[s][e] = (short)hh;
        ql[s][e] = (short)ll;
      }
    }
    __syncthreads();   // all waves done with qtmp before buf1 gets tile 1

    float4v acc[4];
    #pragma unroll
    for(int j=0;j<4;j++) acc[j] = (float4v){0.f,0.f,0.f,0.f};
    float lsum = 0.f;

    for(int t = 0; t < 16; ++t){
      const unsigned int* kcur = knd + ((t & 1) << 14);   // current tile buffer

      // issue tile t+1 FIRST (other buffer; wraps to tile 0 across iters),
      // then counted wait: vmcnt(8) leaves the 8 new loads in flight and
      // waits exactly the 8 oldest (= tile t; vmem retires in order).
      if(!(iter == 2 && t == 15)){
        const int tn = (t + 1) & 15;
        const unsigned int* gsrc = kwv + (size_t)tn*16384;
        unsigned int* ldst = lwv + (((t + 1) & 1) << 14);
        #pragma unroll
        for(int g=0; g<8; ++g) gll16(gsrc + g*256, ldst + g*256);
        asm volatile("s_waitcnt vmcnt(8)" ::: "memory");
      } else {
        asm volatile("s_waitcnt vmcnt(0)" ::: "memory");
      }
      __builtin_amdgcn_sched_barrier(0);

      // ---- QK: s1 rows rA-group, s2 rows rB-group ----
      float4v s1 = (float4v){0.f,0.f,0.f,0.f};
      float4v s2 = (float4v){0.f,0.f,0.f,0.f};
      #pragma unroll
      for(int s = 0; s < 2; ++s){
        const int c0 = s*32 + quad*8;
        uint4v w0 = *(const uint4v*)(kcur + rowA*64 + ((c0    ) ^ phiA));
        uint4v w1 = *(const uint4v*)(kcur + rowA*64 + ((c0 + 4) ^ phiA));
        uint4v u0 = *(const uint4v*)(kcur + rowB*64 + ((c0    ) ^ phiB));
        uint4v u1 = *(const uint4v*)(kcur + rowB*64 + ((c0 + 4) ^ phiB));
        bf16x8 a1h, a1l, a2h, a2l;
        #pragma unroll
        for(int j = 0; j < 4; ++j){
          a1h[j]   = (short)(w0[j] & 0xffffu);  a1l[j]   = (short)(w0[j] >> 16);
          a1h[j+4] = (short)(w1[j] & 0xffffu);  a1l[j+4] = (short)(w1[j] >> 16);
          a2h[j]   = (short)(u0[j] & 0xffffu);  a2l[j]   = (short)(u0[j] >> 16);
          a2h[j+4] = (short)(u1[j] & 0xffffu);  a2l[j+4] = (short)(u1[j] >> 16);
        }
        s1 = __builtin_amdgcn_mfma_f32_16x16x32_bf16(a1h, qh[s], s1, 0,0,0);
        s1 = __builtin_amdgcn_mfma_f32_16x16x32_bf16(a1l, qh[s], s1, 0,0,0);
        s1 = __builtin_amdgcn_mfma_f32_16x16x32_bf16(a1h, ql[s], s1, 0,0,0);
        s2 = __builtin_amdgcn_mfma_f32_16x16x32_bf16(a2h, qh[s], s2, 0,0,0);
        s2 = __builtin_amdgcn_mfma_f32_16x16x32_bf16(a2l, qh[s], s2, 0,0,0);
        s2 = __builtin_amdgcn_mfma_f32_16x16x32_bf16(a2h, ql[s], s2, 0,0,0);
      }

      // ---- exp + split P in registers (D-layout == PV A-layout) ----
      bf16x8 pa_h, pa_l;
      #pragma unroll
      for(int e = 0; e < 4; ++e){
        float v = __expf(s1[e]);
        lsum += v;
        unsigned int hh, ll;
        splitbf(v, hh, ll);
        pa_h[e] = (short)hh;
        pa_l[e] = (short)ll;
        float v2 = __expf(s2[e]);
        lsum += v2;
        splitbf(v2, hh, ll);
        pa_h[e+4] = (short)hh;
        pa_l[e+4] = (short)ll;
      }

      // ---- PV over wave's 32 rows (K=32), wave-local reads ----
      const int rb0 = wave*32 + quad*8;
      #pragma unroll
      for(int j = 0; j < 4; ++j){
        bf16x8 kbh, kbl;
        #pragma unroll
        for(int e = 0; e < 8; ++e){
          const int jx = ((e >> 2) ^ q1) & 1;
          unsigned int w = kcur[(rb0 + e)*64 + ((j ^ jx) << 4) + (l16 ^ ((e & 3) << 2))];
          kbh[e] = (short)(w & 0xffffu);
          kbl[e] = (short)(w >> 16);
        }
        acc[j] = __builtin_amdgcn_mfma_f32_16x16x32_bf16(pa_h, kbh, acc[j], 0,0,0);
        acc[j] = __builtin_amdgcn_mfma_f32_16x16x32_bf16(pa_l, kbh, acc[j], 0,0,0);
        acc[j] = __builtin_amdgcn_mfma_f32_16x16x32_bf16(pa_h, kbl, acc[j], 0,0,0);
      }
    } // rounds

    // ---- iteration boundary: block reduction + renorm ----
    __syncthreads();   // all waves done with buf1 (scratch region) tiles
    lsum += __shfl_xor(lsum, 16);
    lsum += __shfl_xor(lsum, 32);
    if(quad == 0) lredf[wave*16 + l16] = lsum;
    #pragma unroll
    for(int j = 0; j < 4; ++j)
      #pragma unroll
      for(int r = 0; r < 4; ++r)
        accf[wave*1024 + (quad*4 + r)*64 + j*16 + l16] = acc[j][r];
    __syncthreads();
    #pragma unroll
    for(int k = 0; k < 2; ++k){
      const int i = tid + k*512;          // 0..1023 : l=i>>6, d=i&63
      const int l = i >> 6, d = i & 63;
      float s = 0.f, lt = 1.f;
      #pragma unroll
      for(int w = 0; w < 8; ++w){ s += accf[w*1024 + i]; }
      #pragma unroll
      for(int w = 0; w < 8; ++w){ lt += lredf[w*16 + l]; }
      const float qv = s / lt;
      if(iter < 2) qtmp[i] = qv;
      else qcur[(size_t)(b*16 + l)*768 + h*64 + d] = qv;
    }
    __syncthreads();   // qtmp visible to all waves before next frag build
  } // iterations
}

// ---------------------------------------------------------------------------
// out[r][c] = sum_j inp[r][j]*W[c][j] (+bias). 4 rows x 256 cols per block.
// ---------------------------------------------------------------------------
__global__ __launch_bounds__(256)
void proj_kernel(const float* __restrict__ inp, const float* __restrict__ w,
                 const float* __restrict__ bias, float* __restrict__ out){
  __shared__ float rows[4*768];
  const int r0 = blockIdx.x*4;
  const int c  = blockIdx.y*256 + threadIdx.x;
  for(int j = threadIdx.x; j < 4*768; j += 256) rows[j] = inp[(size_t)r0*768 + j];
  __syncthreads();
  const float* wr = w + (size_t)c*768;
  float a0=0.f, a1=0.f, a2=0.f, a3=0.f;
  for(int j=0;j<768;j+=4){
    float4v w4 = *(const float4v*)(wr+j);
    float4v r0v = *(const float4v*)(rows+j);
    float4v r1v = *(const float4v*)(rows+768+j);
    float4v r2v = *(const float4v*)(rows+1536+j);
    float4v r3v = *(const float4v*)(rows+2304+j);
    #pragma unroll
    for(int e=0;e<4;e++){
      a0 += r0v[e]*w4[e]; a1 += r1v[e]*w4[e];
      a2 += r2v[e]*w4[e]; a3 += r3v[e]*w4[e];
    }
  }
  const float bb = bias ? bias[c] : 0.f;
  out[(size_t)(r0+0)*768 + c] = a0 + bb;
  out[(size_t)(r0+1)*768 + c] = a1 + bb;
  out[(size_t)(r0+2)*768 + c] = a2 + bb;
  out[(size_t)(r0+3)*768 + c] = a3 + bb;
}

// ---------------------------------------------------------------------------
extern "C" void kernel_launch(void* const* d_in, const int* in_sizes, int n_in,
                              void* d_out, int out_size, void* d_ws, size_t ws_size,
                              hipStream_t stream){
  const float* x     = (const float*)d_in[0];   // [16,4096,768]
  const float* query = (const float*)d_in[1];   // [1,16,768]
  const float* Wq    = (const float*)d_in[2];   // [768,768]
  const float* Wk    = (const float*)d_in[3];
  const float* Wv    = (const float*)d_in[4];
  const float* Wproj = (const float*)d_in[5];
  const float* bproj = (const float*)d_in[6];   // [768]
  float* out = (float*)d_out;                   // [16,16,768] fp32

  char* ws = (char*)d_ws;
  unsigned int*   khead = (unsigned int*)(ws);           // 201326592 B
  float*          qcur  = (float*)(ws + 201326592);      // 786432 B
  float*          q0    = (float*)(ws + 202113024);      // 49152 B
  char*           R     = ws + 202162176;                // 2359296 B region
  unsigned short* wkh   = (unsigned short*)(R);          // gemm phase
  unsigned short* wkl   = (unsigned short*)(R + 1179648);
  float*          out1  = (float*)(R);                   // proj phase (alias)

  prep_kernel<<<624, 256, 0, stream>>>(Wk, wkh, wkl, query, Wq, q0);
  gemm_k_kernel<<<3072, 256, 0, stream>>>(x, wkh, wkl, khead);

  attn3_kernel<<<192, 512, 0, stream>>>(khead, q0, qcur);

  proj_kernel<<<dim3(64, 3), 256, 0, stream>>>(qcur, Wv, nullptr, out1);
  proj_kernel<<<dim3(64, 3), 256, 0, stream>>>(out1, Wproj, bproj, out);
}